// Round 13
// baseline (413.725 us; speedup 1.0000x reference)
//
#include <hip/hip_runtime.h>
#include <hip/hip_bf16.h>
#include <math.h>

// ---------------- problem constants ----------------
constexpr int NN   = 50000;        // nodes (= 3125 * 16, no MFMA tail)
constexpr int N2   = 2*NN;         // both encoders batched
constexpr int EE   = 400000;       // edges (before self loops)
constexpr int DIN  = 256;          // input dim
constexpr int M1   = 128;          // heads*H1
constexpr int H1N  = 4;            // heads layer 1
constexpr int M2   = 64;           // H2
constexpr int BP   = 4096;         // entity pairs
constexpr int DEC  = 512;          // decoder hidden
constexpr float SLOPE = 0.2f;

// output layout (flat, fp32)
constexpr int O_LOG    = 0;
constexpr int O_RETOS  = 8192;
constexpr int O_RETOSA = 108192;
constexpr int O_X2     = 208192;
constexpr int O_LOGITS = 3408192;
constexpr int O_LOG1   = 3508192;

constexpr int SCAN_NB = (NN + 1023) / 1024;

typedef __attribute__((ext_vector_type(8))) short short8;   // 8 bf16 = 4 VGPRs
typedef __attribute__((ext_vector_type(4))) float f32x4;

__device__ __forceinline__ short f2bs(float v){
    __hip_bfloat16 h = __float2bfloat16(v);
    unsigned short u; __builtin_memcpy(&u, &h, 2);
    return (short)u;
}
__device__ __forceinline__ float lrelu(float e){ return (e >= 0.f) ? e : SLOPE*e; }

// ---------------- CSR build ----------------
__global__ void hist_dst(const int* __restrict__ edst, int* __restrict__ cnt){
    int i = blockIdx.x*blockDim.x + threadIdx.x;
    if (i < EE) atomicAdd(&cnt[edst[i]], 1);
}

__global__ __launch_bounds__(1024) void scan_blk(const int* __restrict__ cnt,
                                                 int* __restrict__ rowex,
                                                 int* __restrict__ bsum){
    __shared__ int wsum[16];
    const int t = threadIdx.x;
    const int idx = blockIdx.x*1024 + t;
    const int lane = t & 63, wid = t >> 6;
    int v = (idx < NN) ? cnt[idx] : 0;
    int s = v;
    #pragma unroll
    for (int o = 1; o < 64; o <<= 1){
        int u = __shfl_up(s, o, 64);
        if (lane >= o) s += u;
    }
    if (lane == 63) wsum[wid] = s;
    __syncthreads();
    if (wid == 0){
        int ws = (lane < 16) ? wsum[lane] : 0;
        #pragma unroll
        for (int o = 1; o < 16; o <<= 1){
            int u = __shfl_up(ws, o, 64);
            if (lane >= o) ws += u;
        }
        if (lane < 16) wsum[lane] = ws;
    }
    __syncthreads();
    int base = (wid > 0) ? wsum[wid-1] : 0;
    int incl = base + s;
    if (idx < NN) rowex[idx] = incl - v;
    if (t == 1023) bsum[blockIdx.x] = incl;
}

__global__ void scan_bsum(int* __restrict__ bsum, int nb){
    const int lane = threadIdx.x;
    int v = (lane < nb) ? bsum[lane] : 0;
    int s = v;
    #pragma unroll
    for (int o = 1; o < 64; o <<= 1){
        int u = __shfl_up(s, o, 64);
        if (lane >= o) s += u;
    }
    if (lane < nb) bsum[lane] = s - v;
}

__global__ void scan_fix(int* __restrict__ row, const int* __restrict__ bsum,
                         int* __restrict__ cursor){
    int idx = blockIdx.x*blockDim.x + threadIdx.x;
    if (idx < NN){
        int r = row[idx] + bsum[idx >> 10];
        row[idx] = r;
        cursor[idx] = r;
    }
    if (idx == 0) row[NN] = EE;
}

__global__ void fill_csr(const int* __restrict__ esrc, const int* __restrict__ edst,
                         int* __restrict__ cursor, int* __restrict__ adj){
    int i = blockIdx.x*blockDim.x + threadIdx.x;
    if (i >= EE) return;
    int d = edst[i];
    int slot = atomicAdd(&cursor[d], 1);
    adj[slot] = esrc[i];
}

// ---------------- W pack (all three weights, one launch) ----------------
// fp32 [K][M] -> bf16 B-fragment layout
__device__ __forceinline__ void pack_one(const float* __restrict__ W,
                                         __hip_bfloat16* __restrict__ Wpk,
                                         int i, int M){
    int k = i / M, c = i - k*M;
    int kb = k >> 5, r = k & 31, quad = r >> 3, j = r & 7;
    int ct = c >> 4, ln = quad*16 + (c & 15);
    int CT = M >> 4;
    size_t dst = (((size_t)kb*CT + ct)*64 + ln)*8 + j;
    Wpk[dst] = __float2bfloat16(W[i]);
}

__global__ void pack_all(const float* __restrict__ W1, const float* __restrict__ W2,
                         const float* __restrict__ fW1,
                         __hip_bfloat16* __restrict__ Wpk1,
                         __hip_bfloat16* __restrict__ Wpk2,
                         __hip_bfloat16* __restrict__ Wpkf){
    constexpr int S1 = DIN*M1;           // 32768
    constexpr int S2 = S1 + M1*M2;       // 40960
    constexpr int S3 = S2 + M1*DEC;      // 106496
    int i = blockIdx.x*blockDim.x + threadIdx.x;
    if (i < S1)       pack_one(W1,  Wpk1, i,      M1);
    else if (i < S2)  pack_one(W2,  Wpk2, i - S1, M2);
    else if (i < S3)  pack_one(fW1, Wpkf, i - S2, DEC);
}

// ---------------- MFMA GEMM + fused attention scores ----------------
// R13: LDS W staging + 4 TILES PER WAVE. R5 vs R12 showed the invariant
// time ~= exposed-latency / waves-per-SIMD: LDS halved the chain but the
// 64KB LDS halved occupancy (2 blk/CU -> 2 waves/SIMD) -- product flat.
// 4 tiles/wave: 8 A-loads in flight, 32 MFMA/kb-step, W ds_reads shared
// 4x. kb loop stays "#pragma unroll 1" (R9/R10 lesson: unroll re-hoists
// the prefetch into a full-K spill). ~200 VGPR, legal under the 256 cap
// that 2 blocks/CU affords.
template<int K, int M, int HEADS_T, bool AF32>
__global__ __launch_bounds__(256, 2) void gemm_attn(
        const void* __restrict__ X0, const void* __restrict__ X1,
        const __hip_bfloat16* __restrict__ Wpk,
        const float* __restrict__ asrc, const float* __restrict__ adst,
        __hip_bfloat16* __restrict__ Hb,
        float* __restrict__ AS, float* __restrict__ AD){
    constexpr int CT = M/16;
    constexpr int KB = K/32;
    constexpr int CPH = CT/HEADS_T;          // ct-blocks per head
    constexpr int NG = (N2/16 + 3)/4;        // 4-tile groups (1563)
    __shared__ __hip_bfloat16 Wl[K*M];       // packed W, block-shared

    // cooperative coalesced LDS fill (16B per thread-iter)
    {
        short8* dstv = (short8*)Wl;
        const short8* srcv = (const short8*)Wpk;
        for (int i = threadIdx.x; i < K*M/8; i += 256)
            dstv[i] = srcv[i];
    }
    __syncthreads();

    const int wave0 = (blockIdx.x*256 + threadIdx.x) >> 6;
    const int nwv   = (gridDim.x*256) >> 6;
    const int lane  = threadIdx.x & 63;
    const int arow  = lane & 15;
    const int quad  = lane >> 4;

    for (int grp = wave0; grp < NG; grp += nwv){
        const int tb = grp*4;                 // first tile of group

        bool val[4];
        const float* apf[4];
        const __hip_bfloat16* apb[4];
        #pragma unroll
        for (int t = 0; t < 4; ++t){
            const int n0 = (tb + t)*16;
            val[t] = (n0 < N2);
            const int n0c = val[t] ? n0 : 0;  // clamp invalid tiles to row 0
            if constexpr (AF32){
                apf[t] = ((n0c < NN) ? ((const float*)X0 + (size_t)(n0c + arow)*K)
                                     : ((const float*)X1 + (size_t)(n0c - NN + arow)*K)) + quad*8;
            } else {
                apb[t] = (const __hip_bfloat16*)X0 + (size_t)(n0c + arow)*K + quad*8;
            }
        }

        // prefetch kb=0 raw A for all 4 tiles (8 loads in flight)
        float4 ra0[4], ra1[4];
        short8 rb[4];
        #pragma unroll
        for (int t = 0; t < 4; ++t){
            if constexpr (AF32){
                ra0[t] = *(const float4*)(apf[t]);
                ra1[t] = *(const float4*)(apf[t] + 4);
            } else {
                rb[t] = *(const short8*)(apb[t]);
            }
        }

        f32x4 acc[4][CT];
        #pragma unroll
        for (int t = 0; t < 4; ++t)
            #pragma unroll
            for (int ct = 0; ct < CT; ++ct) acc[t][ct] = (f32x4){0.f,0.f,0.f,0.f};

        #pragma unroll 1
        for (int kb = 0; kb < KB; ++kb){
            short8 af[4];
            #pragma unroll
            for (int t = 0; t < 4; ++t){
                if constexpr (AF32){
                    af[t][0]=f2bs(ra0[t].x); af[t][1]=f2bs(ra0[t].y);
                    af[t][2]=f2bs(ra0[t].z); af[t][3]=f2bs(ra0[t].w);
                    af[t][4]=f2bs(ra1[t].x); af[t][5]=f2bs(ra1[t].y);
                    af[t][6]=f2bs(ra1[t].z); af[t][7]=f2bs(ra1[t].w);
                } else {
                    af[t] = rb[t];
                }
            }
            if (kb + 1 < KB){   // issue next-step A loads before the MFMAs
                const int kn = (kb + 1)*32;
                #pragma unroll
                for (int t = 0; t < 4; ++t){
                    if constexpr (AF32){
                        ra0[t] = *(const float4*)(apf[t] + kn);
                        ra1[t] = *(const float4*)(apf[t] + kn + 4);
                    } else {
                        rb[t] = *(const short8*)(apb[t] + kn);
                    }
                }
            }
            const __hip_bfloat16* wl = Wl + (size_t)kb*CT*64*8;
            #pragma unroll
            for (int ct = 0; ct < CT; ++ct){
                short8 bfr = *(const short8*)(wl + ((size_t)ct*64 + lane)*8);
                #pragma unroll
                for (int t = 0; t < 4; ++t)
                    acc[t][ct] = __builtin_amdgcn_mfma_f32_16x16x32_bf16(af[t], bfr, acc[t][ct], 0, 0, 0);
            }
        }

        // epilogue: H write + attention scores per tile (guards wave-uniform)
        float a_s[CT], a_d[CT];
        #pragma unroll
        for (int ct = 0; ct < CT; ++ct){
            a_s[ct] = asrc[ct*16 + arow];
            a_d[ct] = adst[ct*16 + arow];
        }
        #pragma unroll
        for (int t = 0; t < 4; ++t){
            if (!val[t]) continue;
            const int n0 = (tb + t)*16;
            #pragma unroll
            for (int ct = 0; ct < CT; ++ct){
                #pragma unroll
                for (int r = 0; r < 4; ++r){
                    int n = n0 + quad*4 + r;
                    Hb[(size_t)n*M + ct*16 + arow] = __float2bfloat16(acc[t][ct][r]);
                }
            }
            #pragma unroll
            for (int r = 0; r < 4; ++r){
                const int n = n0 + quad*4 + r;
                #pragma unroll
                for (int h = 0; h < HEADS_T; ++h){
                    float ss = 0.f, dd = 0.f;
                    #pragma unroll
                    for (int c2 = 0; c2 < CPH; ++c2){
                        int ct = h*CPH + c2;
                        ss += acc[t][ct][r]*a_s[ct];
                        dd += acc[t][ct][r]*a_d[ct];
                    }
                    #pragma unroll
                    for (int o = 8; o > 0; o >>= 1){
                        ss += __shfl_down(ss, o, 16);
                        dd += __shfl_down(dd, o, 16);
                    }
                    if (arow == 0){
                        AS[(size_t)n*HEADS_T + h] = ss;
                        AD[(size_t)n*HEADS_T + h] = dd;
                    }
                }
            }
        }
    }
}

// ---------------- GAT aggregation: 8-wide edge pipeline ----------------
__global__ __launch_bounds__(256) void gat_agg_l1(
        const int* __restrict__ row, const int* __restrict__ adj,
        const __hip_bfloat16* __restrict__ Hfeat,
        const float* __restrict__ AS, const float* __restrict__ AD,
        const float* __restrict__ b, const float* __restrict__ p,
        __hip_bfloat16* __restrict__ outB){
    const int wv = (blockIdx.x*blockDim.x + threadIdx.x) >> 6;
    const int nw = (gridDim.x*blockDim.x) >> 6;
    const int t = threadIdx.x & 63;     // col pair t -> cols 2t, 2t+1
    const int h = t >> 4;               // 32 cols per head -> 16 threads per head
    const unsigned* Hw = (const unsigned*)Hfeat;
    const float bb0 = b[2*t], bb1 = b[2*t+1];
    const float pp0 = p[2*t], pp1 = p[2*t+1];
    for (int nd = wv; nd < N2; nd += nw){
        const int g  = (nd < NN) ? nd : nd - NN;   // graph node
        const int fb = nd - g;                     // feature-row base (0 or NN)
        const float ad_h = AD[(size_t)nd*4 + h];
        float acc0, acc1, den;
        {   // self loop
            float ws = __expf(lrelu(AS[(size_t)nd*4 + h] + ad_h));
            unsigned u = Hw[(size_t)nd*64 + t];
            acc0 = __uint_as_float(u << 16) * ws;
            acc1 = __uint_as_float(u & 0xffff0000u) * ws;
            den = ws;
        }
        const int beg = row[g], end = row[g+1];
        int j = beg;
        for (; j + 7 < end; j += 8){
            int s0 = adj[j]   + fb; int s1 = adj[j+1] + fb;
            int s2 = adj[j+2] + fb; int s3 = adj[j+3] + fb;
            int s4 = adj[j+4] + fb; int s5 = adj[j+5] + fb;
            int s6 = adj[j+6] + fb; int s7 = adj[j+7] + fb;
            float e0 = AS[(size_t)s0*4 + h]; float e1 = AS[(size_t)s1*4 + h];
            float e2 = AS[(size_t)s2*4 + h]; float e3 = AS[(size_t)s3*4 + h];
            float e4 = AS[(size_t)s4*4 + h]; float e5 = AS[(size_t)s5*4 + h];
            float e6 = AS[(size_t)s6*4 + h]; float e7 = AS[(size_t)s7*4 + h];
            unsigned u0 = Hw[(size_t)s0*64 + t]; unsigned u1 = Hw[(size_t)s1*64 + t];
            unsigned u2 = Hw[(size_t)s2*64 + t]; unsigned u3 = Hw[(size_t)s3*64 + t];
            unsigned u4 = Hw[(size_t)s4*64 + t]; unsigned u5 = Hw[(size_t)s5*64 + t];
            unsigned u6 = Hw[(size_t)s6*64 + t]; unsigned u7 = Hw[(size_t)s7*64 + t];
            float w0 = __expf(lrelu(e0 + ad_h)); float w1 = __expf(lrelu(e1 + ad_h));
            float w2 = __expf(lrelu(e2 + ad_h)); float w3 = __expf(lrelu(e3 + ad_h));
            float w4 = __expf(lrelu(e4 + ad_h)); float w5 = __expf(lrelu(e5 + ad_h));
            float w6 = __expf(lrelu(e6 + ad_h)); float w7 = __expf(lrelu(e7 + ad_h));
            acc0 += __uint_as_float(u0 << 16) * w0;
            acc1 += __uint_as_float(u0 & 0xffff0000u) * w0;
            acc0 += __uint_as_float(u1 << 16) * w1;
            acc1 += __uint_as_float(u1 & 0xffff0000u) * w1;
            acc0 += __uint_as_float(u2 << 16) * w2;
            acc1 += __uint_as_float(u2 & 0xffff0000u) * w2;
            acc0 += __uint_as_float(u3 << 16) * w3;
            acc1 += __uint_as_float(u3 & 0xffff0000u) * w3;
            acc0 += __uint_as_float(u4 << 16) * w4;
            acc1 += __uint_as_float(u4 & 0xffff0000u) * w4;
            acc0 += __uint_as_float(u5 << 16) * w5;
            acc1 += __uint_as_float(u5 & 0xffff0000u) * w5;
            acc0 += __uint_as_float(u6 << 16) * w6;
            acc1 += __uint_as_float(u6 & 0xffff0000u) * w6;
            acc0 += __uint_as_float(u7 << 16) * w7;
            acc1 += __uint_as_float(u7 & 0xffff0000u) * w7;
            den += w0 + w1 + w2 + w3 + w4 + w5 + w6 + w7;
        }
        for (; j + 3 < end; j += 4){
            int s0 = adj[j]   + fb; int s1 = adj[j+1] + fb;
            int s2 = adj[j+2] + fb; int s3 = adj[j+3] + fb;
            float e0 = AS[(size_t)s0*4 + h]; float e1 = AS[(size_t)s1*4 + h];
            float e2 = AS[(size_t)s2*4 + h]; float e3 = AS[(size_t)s3*4 + h];
            unsigned u0 = Hw[(size_t)s0*64 + t]; unsigned u1 = Hw[(size_t)s1*64 + t];
            unsigned u2 = Hw[(size_t)s2*64 + t]; unsigned u3 = Hw[(size_t)s3*64 + t];
            float w0 = __expf(lrelu(e0 + ad_h)); float w1 = __expf(lrelu(e1 + ad_h));
            float w2 = __expf(lrelu(e2 + ad_h)); float w3 = __expf(lrelu(e3 + ad_h));
            acc0 += __uint_as_float(u0 << 16) * w0;
            acc1 += __uint_as_float(u0 & 0xffff0000u) * w0;
            acc0 += __uint_as_float(u1 << 16) * w1;
            acc1 += __uint_as_float(u1 & 0xffff0000u) * w1;
            acc0 += __uint_as_float(u2 << 16) * w2;
            acc1 += __uint_as_float(u2 & 0xffff0000u) * w2;
            acc0 += __uint_as_float(u3 << 16) * w3;
            acc1 += __uint_as_float(u3 & 0xffff0000u) * w3;
            den += w0 + w1 + w2 + w3;
        }
        for (; j < end; ++j){
            int s = adj[j] + fb;
            float wgt = __expf(lrelu(AS[(size_t)s*4 + h] + ad_h));
            unsigned u = Hw[(size_t)s*64 + t];
            acc0 += __uint_as_float(u << 16) * wgt;
            acc1 += __uint_as_float(u & 0xffff0000u) * wgt;
            den += wgt;
        }
        float inv = 1.f/(den + 1e-16f);
        float v0 = acc0*inv + bb0;
        float v1 = acc1*inv + bb1;
        v0 = (v0 >= 0.f) ? v0 : pp0*v0;
        v1 = (v1 >= 0.f) ? v1 : pp1*v1;
        ushort2 st = make_ushort2((unsigned short)f2bs(v0), (unsigned short)f2bs(v1));
        *(ushort2*)(outB + (size_t)nd*128 + 2*t) = st;
    }
}

__global__ __launch_bounds__(256) void gat_agg_l2(
        const int* __restrict__ row, const int* __restrict__ adj,
        const __hip_bfloat16* __restrict__ Hfeat,
        const float* __restrict__ AS, const float* __restrict__ AD,
        const float* __restrict__ b, const float* __restrict__ p,
        float* __restrict__ outO, float* __restrict__ outA){
    const int wv = (blockIdx.x*blockDim.x + threadIdx.x) >> 6;
    const int nw = (gridDim.x*blockDim.x) >> 6;
    const int t = threadIdx.x & 63;
    const float bb = b[t], pp = p[t];
    const ushort* Hu = (const ushort*)Hfeat;
    for (int nd = wv; nd < N2; nd += nw){
        const int g  = (nd < NN) ? nd : nd - NN;
        const int fb = nd - g;
        const float ad_d = AD[nd];
        float acc, den;
        {   // self loop
            float ws = __expf(lrelu(AS[nd] + ad_d));
            unsigned u = Hu[(size_t)nd*64 + t];
            acc = __uint_as_float(u << 16) * ws;
            den = ws;
        }
        const int beg = row[g], end = row[g+1];
        int j = beg;
        for (; j + 7 < end; j += 8){
            int s0 = adj[j]   + fb; int s1 = adj[j+1] + fb;
            int s2 = adj[j+2] + fb; int s3 = adj[j+3] + fb;
            int s4 = adj[j+4] + fb; int s5 = adj[j+5] + fb;
            int s6 = adj[j+6] + fb; int s7 = adj[j+7] + fb;
            float e0 = AS[s0]; float e1 = AS[s1];
            float e2 = AS[s2]; float e3 = AS[s3];
            float e4 = AS[s4]; float e5 = AS[s5];
            float e6 = AS[s6]; float e7 = AS[s7];
            unsigned u0 = Hu[(size_t)s0*64 + t]; unsigned u1 = Hu[(size_t)s1*64 + t];
            unsigned u2 = Hu[(size_t)s2*64 + t]; unsigned u3 = Hu[(size_t)s3*64 + t];
            unsigned u4 = Hu[(size_t)s4*64 + t]; unsigned u5 = Hu[(size_t)s5*64 + t];
            unsigned u6 = Hu[(size_t)s6*64 + t]; unsigned u7 = Hu[(size_t)s7*64 + t];
            float w0 = __expf(lrelu(e0 + ad_d)); float w1 = __expf(lrelu(e1 + ad_d));
            float w2 = __expf(lrelu(e2 + ad_d)); float w3 = __expf(lrelu(e3 + ad_d));
            float w4 = __expf(lrelu(e4 + ad_d)); float w5 = __expf(lrelu(e5 + ad_d));
            float w6 = __expf(lrelu(e6 + ad_d)); float w7 = __expf(lrelu(e7 + ad_d));
            acc += __uint_as_float(u0 << 16) * w0;
            acc += __uint_as_float(u1 << 16) * w1;
            acc += __uint_as_float(u2 << 16) * w2;
            acc += __uint_as_float(u3 << 16) * w3;
            acc += __uint_as_float(u4 << 16) * w4;
            acc += __uint_as_float(u5 << 16) * w5;
            acc += __uint_as_float(u6 << 16) * w6;
            acc += __uint_as_float(u7 << 16) * w7;
            den += w0 + w1 + w2 + w3 + w4 + w5 + w6 + w7;
        }
        for (; j + 3 < end; j += 4){
            int s0 = adj[j]   + fb; int s1 = adj[j+1] + fb;
            int s2 = adj[j+2] + fb; int s3 = adj[j+3] + fb;
            float e0 = AS[s0]; float e1 = AS[s1];
            float e2 = AS[s2]; float e3 = AS[s3];
            unsigned u0 = Hu[(size_t)s0*64 + t]; unsigned u1 = Hu[(size_t)s1*64 + t];
            unsigned u2 = Hu[(size_t)s2*64 + t]; unsigned u3 = Hu[(size_t)s3*64 + t];
            float w0 = __expf(lrelu(e0 + ad_d)); float w1 = __expf(lrelu(e1 + ad_d));
            float w2 = __expf(lrelu(e2 + ad_d)); float w3 = __expf(lrelu(e3 + ad_d));
            acc += __uint_as_float(u0 << 16) * w0;
            acc += __uint_as_float(u1 << 16) * w1;
            acc += __uint_as_float(u2 << 16) * w2;
            acc += __uint_as_float(u3 << 16) * w3;
            den += w0 + w1 + w2 + w3;
        }
        for (; j < end; ++j){
            int s = adj[j] + fb;
            float wgt = __expf(lrelu(AS[s] + ad_d));
            unsigned u = Hu[(size_t)s*64 + t];
            acc += __uint_as_float(u << 16) * wgt;
            den += wgt;
        }
        float v = acc/(den + 1e-16f) + bb;
        v = (v >= 0.f) ? v : pp*v;
        if (nd < NN) outO[(size_t)nd*64 + t] = v;
        else         outA[(size_t)(nd - NN)*64 + t] = v;
    }
}

// ---------------- both column sums in one launch ----------------
__global__ __launch_bounds__(256) void colsum2(const float* __restrict__ Xo,
                                               const float* __restrict__ Xa,
                                               float* __restrict__ outO,
                                               float* __restrict__ outA){
    __shared__ float red[2][256];
    const int t = threadIdx.x;
    const int c = t & 63;
    const int rg = t >> 6;
    float so = 0.f, sa = 0.f;
    for (int r = blockIdx.x*4 + rg; r < NN; r += gridDim.x*4){
        so += Xo[(size_t)r*64 + c];
        sa += Xa[(size_t)r*64 + c];
    }
    red[0][t] = so; red[1][t] = sa; __syncthreads();
    if (t < 64){
        atomicAdd(&outO[c], red[0][t] + red[0][t+64] + red[0][t+128] + red[0][t+192]);
        atomicAdd(&outA[c], red[1][t] + red[1][t+64] + red[1][t+128] + red[1][t+192]);
    }
}

__global__ void summary(const float* __restrict__ csum_o, const float* __restrict__ csum_a,
                        const float* __restrict__ mlpW, const float* __restrict__ mlpb,
                        const float* __restrict__ discW,
                        const float* __restrict__ advW, const float* __restrict__ advb,
                        float* __restrict__ Wc_o, float* __restrict__ Wc_a,
                        float* __restrict__ advRow, float* __restrict__ advbsum){
    __shared__ float s_o[64], s_a[64], h_o[64], h_a[64];
    const int t = threadIdx.x;
    s_o[t] = 1.f/(1.f + expf(-csum_o[t]/(float)NN));
    s_a[t] = 1.f/(1.f + expf(-csum_a[t]/(float)NN));
    __syncthreads();
    float ao = 0.f, aa = 0.f;
    for (int k = 0; k < 64; ++k){ float w = mlpW[k*64 + t]; ao += s_o[k]*w; aa += s_a[k]*w; }
    float bb = mlpb[t];
    h_o[t] = ao + bb; h_a[t] = aa + bb;
    __syncthreads();
    float wo = 0.f, wa = 0.f;
    for (int j = 0; j < 64; ++j){ float w = discW[t*64 + j]; wo += w*h_o[j]; wa += w*h_a[j]; }
    Wc_o[t] = wo; Wc_a[t] = wa;
    float ar = 0.f;
    for (int j = 0; j < 64; ++j) ar += advW[t*64 + j];
    advRow[t] = ar;
    float ab = advb[t];
    for (int o = 32; o > 0; o >>= 1) ab += __shfl_down(ab, o, 64);
    if (t == 0) advbsum[0] = ab;
}

__global__ void node_outputs(const float* __restrict__ x2o, const float* __restrict__ x2a,
                             const float* __restrict__ Wc_o, const float* __restrict__ Wc_a,
                             const float* __restrict__ advRow, const float* __restrict__ advbsum,
                             const float* __restrict__ discb,
                             float* __restrict__ out){
    const int n = blockIdx.x*4 + (threadIdx.x >> 6);
    const int l = threadIdx.x & 63;
    float xo = x2o[(size_t)n*64 + l], xa = x2a[(size_t)n*64 + l];
    float wo = Wc_o[l], wa = Wc_a[l], ar = advRow[l];
    float d1 = xo*wo, d2 = xa*wo, d3 = xa*wa, d4 = xo*wa, d5 = xo*ar, d6 = xa*ar;
    for (int o = 32; o > 0; o >>= 1){
        d1 += __shfl_down(d1, o, 64); d2 += __shfl_down(d2, o, 64);
        d3 += __shfl_down(d3, o, 64); d4 += __shfl_down(d4, o, 64);
        d5 += __shfl_down(d5, o, 64); d6 += __shfl_down(d6, o, 64);
    }
    if (l == 0){
        float db = discb[0];
        float ab = advbsum[0];
        out[O_RETOS  + n*2 + 0] = d1 + db;
        out[O_RETOS  + n*2 + 1] = d2 + db;
        out[O_RETOSA + n*2 + 0] = d3 + db;
        out[O_RETOSA + n*2 + 1] = d4 + db;
        out[O_LOGITS + n]       = d5 + ab;
        out[O_LOGITS + NN + n]  = d6 + ab;
    }
}

// ---------------- fused decoder: MFMA fh + both heads, 16 pairs/block --------
__global__ __launch_bounds__(256) void decoder_fused(
        const float* __restrict__ x2o, const int* __restrict__ idxArr,
        const __hip_bfloat16* __restrict__ Wpkf, const float* __restrict__ fb1,
        const float* __restrict__ fW2, const float* __restrict__ fb2,
        const float* __restrict__ fW3, const float* __restrict__ fb3,
        float* __restrict__ out){
    __shared__ float part[4][16][4];
    const int t = threadIdx.x;
    const int wid = t >> 6, lane = t & 63;
    const int arow = lane & 15, quad = lane >> 4;
    const int p0 = blockIdx.x*16;
    const int i0 = idxArr[p0 + arow];
    const int i1 = idxArr[BP + p0 + arow];

    f32x4 acc[8];
    #pragma unroll
    for (int c = 0; c < 8; ++c) acc[c] = (f32x4){0.f,0.f,0.f,0.f};

    #pragma unroll
    for (int kb = 0; kb < 4; ++kb){
        int src = (kb < 2) ? i0 : i1;
        int koff = (kb & 1)*32 + quad*8;
        const float* ap = x2o + (size_t)src*64 + koff;
        float4 v0 = *(const float4*)ap;
        float4 v1 = *(const float4*)(ap + 4);
        short8 af;
        af[0]=f2bs(v0.x); af[1]=f2bs(v0.y); af[2]=f2bs(v0.z); af[3]=f2bs(v0.w);
        af[4]=f2bs(v1.x); af[5]=f2bs(v1.y); af[6]=f2bs(v1.z); af[7]=f2bs(v1.w);
        const __hip_bfloat16* wp = Wpkf + (size_t)kb*32*64*8;
        #pragma unroll
        for (int c = 0; c < 8; ++c){
            int ct = wid*8 + c;
            short8 bfr = *(const short8*)(wp + ((size_t)ct*64 + lane)*8);
            acc[c] = __builtin_amdgcn_mfma_f32_16x16x32_bf16(af, bfr, acc[c], 0, 0, 0);
        }
    }

    float a0[4] = {0,0,0,0}, a1[4] = {0,0,0,0};
    float c0[4] = {0,0,0,0}, c1[4] = {0,0,0,0};
    #pragma unroll
    for (int c = 0; c < 8; ++c){
        int col = wid*128 + c*16 + arow;
        float bb = fb1[col];
        float w20 = fW2[col*2], w21 = fW2[col*2+1];
        float w30 = fW3[col*2], w31 = fW3[col*2+1];
        #pragma unroll
        for (int r = 0; r < 4; ++r){
            float v = acc[c][r] + bb;
            v = (v > 0.f) ? v : 0.f;
            a0[r] += v*w20; a1[r] += v*w21;
            c0[r] += v*w30; c1[r] += v*w31;
        }
    }
    #pragma unroll
    for (int o = 8; o > 0; o >>= 1){
        #pragma unroll
        for (int r = 0; r < 4; ++r){
            a0[r] += __shfl_down(a0[r], o, 16);
            a1[r] += __shfl_down(a1[r], o, 16);
            c0[r] += __shfl_down(c0[r], o, 16);
            c1[r] += __shfl_down(c1[r], o, 16);
        }
    }
    if (arow == 0){
        #pragma unroll
        for (int r = 0; r < 4; ++r){
            part[wid][quad*4 + r][0] = a0[r];
            part[wid][quad*4 + r][1] = a1[r];
            part[wid][quad*4 + r][2] = c0[r];
            part[wid][quad*4 + r][3] = c1[r];
        }
    }
    __syncthreads();
    if (t < 64){
        int pr = t >> 2, o = t & 3;
        float s = part[0][pr][o] + part[1][pr][o] + part[2][pr][o] + part[3][pr][o];
        int gb = p0 + pr;
        if (o == 0)      out[O_LOG  + gb*2 + 0] = s + fb2[0];
        else if (o == 1) out[O_LOG  + gb*2 + 1] = s + fb2[1];
        else if (o == 2) out[O_LOG1 + gb*2 + 0] = s + fb3[0];
        else             out[O_LOG1 + gb*2 + 1] = s + fb3[1];
    }
}

extern "C" void kernel_launch(void* const* d_in, const int* in_sizes, int n_in,
                              void* d_out, int out_size, void* d_ws, size_t ws_size,
                              hipStream_t stream){
    const float* x_o    = (const float*)d_in[0];
    const float* x_a    = (const float*)d_in[1];
    const int*   edge   = (const int*)d_in[2];
    const int*   idxp   = (const int*)d_in[3];
    const float* W1     = (const float*)d_in[4];
    const float* a_src1 = (const float*)d_in[5];
    const float* a_dst1 = (const float*)d_in[6];
    const float* b1     = (const float*)d_in[7];
    const float* p1     = (const float*)d_in[8];
    const float* W2     = (const float*)d_in[9];
    const float* a_src2 = (const float*)d_in[10];
    const float* a_dst2 = (const float*)d_in[11];
    const float* b2     = (const float*)d_in[12];
    const float* p2     = (const float*)d_in[13];
    const float* mlpW   = (const float*)d_in[14];
    const float* mlpb   = (const float*)d_in[15];
    const float* discW  = (const float*)d_in[16];
    const float* discb  = (const float*)d_in[17];
    const float* advW   = (const float*)d_in[18];
    const float* advb   = (const float*)d_in[19];
    const float* fW1    = (const float*)d_in[20];
    const float* fb1    = (const float*)d_in[21];
    const float* fW2    = (const float*)d_in[22];
    const float* fb2    = (const float*)d_in[23];
    const float* fW3    = (const float*)d_in[24];
    const float* fb3    = (const float*)d_in[25];

    const int* esrc = edge;
    const int* edst = edge + EE;

    // workspace carve-up (fp32 units), ~58 MB total
    float* w = (float*)d_ws;
    size_t off = 0;
    auto alloc = [&](size_t nfloats){ float* p = w + off; off += nfloats; return p; };
    __hip_bfloat16* Hb   = (__hip_bfloat16*)alloc((size_t)N2*M1/2);  // 2N x 128 bf16
    __hip_bfloat16* x1b  = (__hip_bfloat16*)alloc((size_t)N2*M1/2);  // 2N x 128 bf16
    float* asb   = alloc((size_t)N2*H1N);
    float* adb   = alloc((size_t)N2*H1N);
    __hip_bfloat16* Wpk1 = (__hip_bfloat16*)alloc((size_t)DIN*M1/2);
    __hip_bfloat16* Wpk2 = (__hip_bfloat16*)alloc((size_t)M1*M2/2);
    __hip_bfloat16* Wpkf = (__hip_bfloat16*)alloc((size_t)M1*DEC/2);
    int*   cnt   = (int*)alloc(NN);
    int*   row   = (int*)alloc(NN + 1);
    int*   cursor= (int*)alloc(NN);
    int*   adj   = (int*)alloc(EE);
    int*   bsum  = (int*)alloc(SCAN_NB + 1);
    float* smallb= alloc(512);
    float* csum_o = smallb;       float* csum_a = smallb + 64;
    float* Wc_o   = smallb + 128; float* Wc_a   = smallb + 192;
    float* advRow = smallb + 256; float* advbs  = smallb + 320;

    // x2a aliases the x1b region: x1b is dead after the layer-2 GEMM reads it,
    // and x2a is first written by gat_agg_l2 (strictly after). Saves 12.8 MB.
    float* x2a = (float*)x1b;

    float* out = (float*)d_out;
    float* x2o = out + O_X2;   // agg_l2 writes x2o straight into the output

    // ---- CSR build + W packing ----
    hipMemsetAsync(cnt, 0, NN*sizeof(int), stream);
    hipMemsetAsync(smallb, 0, 128*sizeof(float), stream);
    hist_dst<<<(EE + 255)/256, 256, 0, stream>>>(edst, cnt);
    scan_blk<<<SCAN_NB, 1024, 0, stream>>>(cnt, row, bsum);
    scan_bsum<<<1, 64, 0, stream>>>(bsum, SCAN_NB);
    scan_fix<<<(NN + 255)/256, 256, 0, stream>>>(row, bsum, cursor);
    fill_csr<<<(EE + 255)/256, 256, 0, stream>>>(esrc, edst, cursor, adj);
    pack_all<<<(DIN*M1 + M1*M2 + M1*DEC + 255)/256, 256, 0, stream>>>(
        W1, W2, fW1, Wpk1, Wpk2, Wpkf);

    // ---- layer 1 (both encoders batched) ----
    // 512 blocks (64KB LDS, 2 blk/CU); each wave owns a 4-tile group
    gemm_attn<DIN, M1, H1N, true><<<512, 256, 0, stream>>>(
        x_o, x_a, Wpk1, a_src1, a_dst1, Hb, asb, adb);
    gat_agg_l1<<<2048, 256, 0, stream>>>(row, adj, Hb, asb, adb, b1, p1, x1b);

    // ---- layer 2 (both encoders batched) ----
    gemm_attn<M1, M2, 1, false><<<512, 256, 0, stream>>>(
        x1b, nullptr, Wpk2, a_src2, a_dst2, Hb, asb, adb);
    gat_agg_l2<<<2048, 256, 0, stream>>>(row, adj, Hb, asb, adb, b2, p2, x2o, x2a);

    // ---- readout / heads ----
    colsum2<<<256, 256, 0, stream>>>(x2o, x2a, csum_o, csum_a);
    summary<<<1, 64, 0, stream>>>(csum_o, csum_a, mlpW, mlpb, discW, advW, advb,
                                  Wc_o, Wc_a, advRow, advbs);
    node_outputs<<<NN/4, 256, 0, stream>>>(x2o, x2a, Wc_o, Wc_a, advRow, advbs, discb, out);
    decoder_fused<<<BP/16, 256, 0, stream>>>(x2o, idxp, Wpkf, fb1, fW2, fb2, fW3, fb3, out);
}

// Round 15
// 397.927 us; speedup vs baseline: 1.0397x; 1.0397x over previous
//
#include <hip/hip_runtime.h>
#include <hip/hip_bf16.h>
#include <math.h>

// ---------------- problem constants ----------------
constexpr int NN   = 50000;        // nodes (= 3125 * 16, no MFMA tail)
constexpr int N2   = 2*NN;         // both encoders batched
constexpr int EE   = 400000;       // edges (before self loops)
constexpr int DIN  = 256;          // input dim
constexpr int M1   = 128;          // heads*H1
constexpr int H1N  = 4;            // heads layer 1
constexpr int M2   = 64;           // H2
constexpr int BP   = 4096;         // entity pairs
constexpr int DEC  = 512;          // decoder hidden
constexpr float SLOPE = 0.2f;

// output layout (flat, fp32)
constexpr int O_LOG    = 0;
constexpr int O_RETOS  = 8192;
constexpr int O_RETOSA = 108192;
constexpr int O_X2     = 208192;
constexpr int O_LOGITS = 3408192;
constexpr int O_LOG1   = 3508192;

constexpr int SCAN_NB = (NN + 1023) / 1024;   // 49

typedef __attribute__((ext_vector_type(8))) short short8;   // 8 bf16 = 4 VGPRs
typedef __attribute__((ext_vector_type(4))) float f32x4;

__device__ __forceinline__ short f2bs(float v){
    __hip_bfloat16 h = __float2bfloat16(v);
    unsigned short u; __builtin_memcpy(&u, &h, 2);
    return (short)u;
}
__device__ __forceinline__ float lrelu(float e){ return (e >= 0.f) ? e : SLOPE*e; }

// ---------------- CSR build (R12-proven chain) ----------------
__global__ void hist_dst(const int* __restrict__ edst, int* __restrict__ cnt){
    int i = blockIdx.x*blockDim.x + threadIdx.x;
    if (i < EE) atomicAdd(&cnt[edst[i]], 1);
}

__global__ __launch_bounds__(1024) void scan_blk(const int* __restrict__ cnt,
                                                 int* __restrict__ rowex,
                                                 int* __restrict__ bsum){
    __shared__ int wsum[16];
    const int t = threadIdx.x;
    const int idx = blockIdx.x*1024 + t;
    const int lane = t & 63, wid = t >> 6;
    int v = (idx < NN) ? cnt[idx] : 0;
    int s = v;
    #pragma unroll
    for (int o = 1; o < 64; o <<= 1){
        int u = __shfl_up(s, o, 64);
        if (lane >= o) s += u;
    }
    if (lane == 63) wsum[wid] = s;
    __syncthreads();
    if (wid == 0){
        int ws = (lane < 16) ? wsum[lane] : 0;
        #pragma unroll
        for (int o = 1; o < 16; o <<= 1){
            int u = __shfl_up(ws, o, 64);
            if (lane >= o) ws += u;
        }
        if (lane < 16) wsum[lane] = ws;
    }
    __syncthreads();
    int base = (wid > 0) ? wsum[wid-1] : 0;
    int incl = base + s;
    if (idx < NN) rowex[idx] = incl - v;
    if (t == 1023) bsum[blockIdx.x] = incl;
}

__global__ void scan_bsum(int* __restrict__ bsum, int nb){
    const int lane = threadIdx.x;
    int v = (lane < nb) ? bsum[lane] : 0;
    int s = v;
    #pragma unroll
    for (int o = 1; o < 64; o <<= 1){
        int u = __shfl_up(s, o, 64);
        if (lane >= o) s += u;
    }
    if (lane < nb) bsum[lane] = s - v;
}

__global__ void scan_fix(int* __restrict__ row, const int* __restrict__ bsum,
                         int* __restrict__ cursor){
    int idx = blockIdx.x*blockDim.x + threadIdx.x;
    if (idx < NN){
        int r = row[idx] + bsum[idx >> 10];
        row[idx] = r;
        cursor[idx] = r;
    }
    if (idx == 0) row[NN] = EE;
}

__global__ void fill_csr(const int* __restrict__ esrc, const int* __restrict__ edst,
                         int* __restrict__ cursor, int* __restrict__ adj){
    int i = blockIdx.x*blockDim.x + threadIdx.x;
    if (i >= EE) return;
    int d = edst[i];
    int slot = atomicAdd(&cursor[d], 1);
    adj[slot] = esrc[i];
}

// ---------------- W pack (all three weights, one launch) ----------------
__device__ __forceinline__ void pack_one(const float* __restrict__ W,
                                         __hip_bfloat16* __restrict__ Wpk,
                                         int i, int M){
    int k = i / M, c = i - k*M;
    int kb = k >> 5, r = k & 31, quad = r >> 3, j = r & 7;
    int ct = c >> 4, ln = quad*16 + (c & 15);
    int CT = M >> 4;
    size_t dst = (((size_t)kb*CT + ct)*64 + ln)*8 + j;
    Wpk[dst] = __float2bfloat16(W[i]);
}

__global__ void pack_all(const float* __restrict__ W1, const float* __restrict__ W2,
                         const float* __restrict__ fW1,
                         __hip_bfloat16* __restrict__ Wpk1,
                         __hip_bfloat16* __restrict__ Wpk2,
                         __hip_bfloat16* __restrict__ Wpkf){
    constexpr int S1 = DIN*M1;           // 32768
    constexpr int S2 = S1 + M1*M2;       // 40960
    constexpr int S3 = S2 + M1*DEC;      // 106496
    int i = blockIdx.x*blockDim.x + threadIdx.x;
    if (i < S1)       pack_one(W1,  Wpk1, i,      M1);
    else if (i < S2)  pack_one(W2,  Wpk2, i - S1, M2);
    else if (i < S3)  pack_one(fW1, Wpkf, i - S2, DEC);
}

// ---------------- MFMA GEMM + fused attention scores (R12-proven) ----------
template<int K, int M, int HEADS_T, bool AF32>
__global__ __launch_bounds__(256, 2) void gemm_attn(
        const void* __restrict__ X0, const void* __restrict__ X1,
        const __hip_bfloat16* __restrict__ Wpk,
        const float* __restrict__ asrc, const float* __restrict__ adst,
        __hip_bfloat16* __restrict__ Hb,
        float* __restrict__ AS, float* __restrict__ AD){
    constexpr int CT = M/16;
    constexpr int KB = K/32;
    constexpr int CPH = CT/HEADS_T;          // ct-blocks per head
    __shared__ __hip_bfloat16 Wl[K*M];       // packed W, block-shared

    {   // cooperative coalesced LDS fill (16B per thread-iter)
        short8* dstv = (short8*)Wl;
        const short8* srcv = (const short8*)Wpk;
        for (int i = threadIdx.x; i < K*M/8; i += 256)
            dstv[i] = srcv[i];
    }
    __syncthreads();

    const int wave0 = (blockIdx.x*256 + threadIdx.x) >> 6;
    const int nwv   = (gridDim.x*256) >> 6;
    const int lane  = threadIdx.x & 63;
    const int arow  = lane & 15;
    const int quad  = lane >> 4;

    for (int tile = wave0; tile*16 < N2; tile += nwv){
        const int n0 = tile*16;

        const float* apf = nullptr;
        const __hip_bfloat16* apb = nullptr;
        if constexpr (AF32){
            apf = ((n0 < NN) ? ((const float*)X0 + (size_t)(n0 + arow)*K)
                             : ((const float*)X1 + (size_t)(n0 - NN + arow)*K)) + quad*8;
        } else {
            apb = (const __hip_bfloat16*)X0 + (size_t)(n0 + arow)*K + quad*8;
        }

        float4 ra0, ra1;
        short8 rb;
        if constexpr (AF32){
            ra0 = *(const float4*)(apf);
            ra1 = *(const float4*)(apf + 4);
        } else {
            rb = *(const short8*)(apb);
        }

        f32x4 acc[CT];
        #pragma unroll
        for (int ct = 0; ct < CT; ++ct) acc[ct] = (f32x4){0.f,0.f,0.f,0.f};

        #pragma unroll 1
        for (int kb = 0; kb < KB; ++kb){
            short8 af;
            if constexpr (AF32){
                af[0]=f2bs(ra0.x); af[1]=f2bs(ra0.y); af[2]=f2bs(ra0.z); af[3]=f2bs(ra0.w);
                af[4]=f2bs(ra1.x); af[5]=f2bs(ra1.y); af[6]=f2bs(ra1.z); af[7]=f2bs(ra1.w);
            } else {
                af = rb;
            }
            if (kb + 1 < KB){
                const int kn = (kb + 1)*32;
                if constexpr (AF32){
                    ra0 = *(const float4*)(apf + kn);
                    ra1 = *(const float4*)(apf + kn + 4);
                } else {
                    rb = *(const short8*)(apb + kn);
                }
            }
            const __hip_bfloat16* wl = Wl + (size_t)kb*CT*64*8;
            #pragma unroll
            for (int ct = 0; ct < CT; ++ct){
                short8 bfr = *(const short8*)(wl + ((size_t)ct*64 + lane)*8);
                acc[ct] = __builtin_amdgcn_mfma_f32_16x16x32_bf16(af, bfr, acc[ct], 0, 0, 0);
            }
        }

        #pragma unroll
        for (int ct = 0; ct < CT; ++ct){
            #pragma unroll
            for (int r = 0; r < 4; ++r){
                int n = n0 + quad*4 + r;
                Hb[(size_t)n*M + ct*16 + arow] = __float2bfloat16(acc[ct][r]);
            }
        }

        float a_s[CT], a_d[CT];
        #pragma unroll
        for (int ct = 0; ct < CT; ++ct){
            a_s[ct] = asrc[ct*16 + arow];
            a_d[ct] = adst[ct*16 + arow];
        }
        #pragma unroll
        for (int r = 0; r < 4; ++r){
            const int n = n0 + quad*4 + r;
            #pragma unroll
            for (int h = 0; h < HEADS_T; ++h){
                float ss = 0.f, dd = 0.f;
                #pragma unroll
                for (int c2 = 0; c2 < CPH; ++c2){
                    int ct = h*CPH + c2;
                    ss += acc[ct][r]*a_s[ct];
                    dd += acc[ct][r]*a_d[ct];
                }
                #pragma unroll
                for (int o = 8; o > 0; o >>= 1){
                    ss += __shfl_down(ss, o, 16);
                    dd += __shfl_down(dd, o, 16);
                }
                if (arow == 0){
                    AS[(size_t)n*HEADS_T + h] = ss;
                    AD[(size_t)n*HEADS_T + h] = dd;
                }
            }
        }
    }
}

// ---------------- GAT aggregation: o/a-fused, 4-wide edge pipeline ---------
// Both encoder sides share the graph: one wave per graph node g computes
// both (halves adj/row traffic + loop overhead; 8 H-gathers in flight).
__global__ __launch_bounds__(256) void gat_agg_l1(
        const int* __restrict__ row, const int* __restrict__ adj,
        const __hip_bfloat16* __restrict__ Hfeat,
        const float* __restrict__ AS, const float* __restrict__ AD,
        const float* __restrict__ b, const float* __restrict__ p,
        __hip_bfloat16* __restrict__ outB){
    const int wv = (blockIdx.x*blockDim.x + threadIdx.x) >> 6;
    const int nw = (gridDim.x*blockDim.x) >> 6;
    const int t = threadIdx.x & 63;     // col pair t -> cols 2t, 2t+1
    const int h = t >> 4;               // head
    const unsigned* Hw = (const unsigned*)Hfeat;
    const float bb0 = b[2*t], bb1 = b[2*t+1];
    const float pp0 = p[2*t], pp1 = p[2*t+1];
    for (int g = wv; g < NN; g += nw){
        const float adO = AD[(size_t)g*4 + h];
        const float adA = AD[(size_t)(g+NN)*4 + h];
        float aO0, aO1, dO, aA0, aA1, dA;
        {   // self loops (both sides)
            float wsO = __expf(lrelu(AS[(size_t)g*4 + h] + adO));
            float wsA = __expf(lrelu(AS[(size_t)(g+NN)*4 + h] + adA));
            unsigned uO = Hw[(size_t)g*64 + t];
            unsigned uA = Hw[(size_t)(g+NN)*64 + t];
            aO0 = __uint_as_float(uO << 16) * wsO;
            aO1 = __uint_as_float(uO & 0xffff0000u) * wsO;
            aA0 = __uint_as_float(uA << 16) * wsA;
            aA1 = __uint_as_float(uA & 0xffff0000u) * wsA;
            dO = wsO; dA = wsA;
        }
        const int beg = row[g], end = row[g+1];
        int j = beg;
        for (; j + 3 < end; j += 4){
            int s0 = adj[j];   int s1 = adj[j+1];
            int s2 = adj[j+2]; int s3 = adj[j+3];
            float eO0 = AS[(size_t)s0*4 + h];      float eA0 = AS[(size_t)(s0+NN)*4 + h];
            float eO1 = AS[(size_t)s1*4 + h];      float eA1 = AS[(size_t)(s1+NN)*4 + h];
            float eO2 = AS[(size_t)s2*4 + h];      float eA2 = AS[(size_t)(s2+NN)*4 + h];
            float eO3 = AS[(size_t)s3*4 + h];      float eA3 = AS[(size_t)(s3+NN)*4 + h];
            unsigned uO0 = Hw[(size_t)s0*64 + t];  unsigned uA0 = Hw[(size_t)(s0+NN)*64 + t];
            unsigned uO1 = Hw[(size_t)s1*64 + t];  unsigned uA1 = Hw[(size_t)(s1+NN)*64 + t];
            unsigned uO2 = Hw[(size_t)s2*64 + t];  unsigned uA2 = Hw[(size_t)(s2+NN)*64 + t];
            unsigned uO3 = Hw[(size_t)s3*64 + t];  unsigned uA3 = Hw[(size_t)(s3+NN)*64 + t];
            float wO0 = __expf(lrelu(eO0 + adO));  float wA0 = __expf(lrelu(eA0 + adA));
            float wO1 = __expf(lrelu(eO1 + adO));  float wA1 = __expf(lrelu(eA1 + adA));
            float wO2 = __expf(lrelu(eO2 + adO));  float wA2 = __expf(lrelu(eA2 + adA));
            float wO3 = __expf(lrelu(eO3 + adO));  float wA3 = __expf(lrelu(eA3 + adA));
            aO0 += __uint_as_float(uO0 << 16) * wO0;
            aO1 += __uint_as_float(uO0 & 0xffff0000u) * wO0;
            aO0 += __uint_as_float(uO1 << 16) * wO1;
            aO1 += __uint_as_float(uO1 & 0xffff0000u) * wO1;
            aO0 += __uint_as_float(uO2 << 16) * wO2;
            aO1 += __uint_as_float(uO2 & 0xffff0000u) * wO2;
            aO0 += __uint_as_float(uO3 << 16) * wO3;
            aO1 += __uint_as_float(uO3 & 0xffff0000u) * wO3;
            aA0 += __uint_as_float(uA0 << 16) * wA0;
            aA1 += __uint_as_float(uA0 & 0xffff0000u) * wA0;
            aA0 += __uint_as_float(uA1 << 16) * wA1;
            aA1 += __uint_as_float(uA1 & 0xffff0000u) * wA1;
            aA0 += __uint_as_float(uA2 << 16) * wA2;
            aA1 += __uint_as_float(uA2 & 0xffff0000u) * wA2;
            aA0 += __uint_as_float(uA3 << 16) * wA3;
            aA1 += __uint_as_float(uA3 & 0xffff0000u) * wA3;
            dO += wO0 + wO1 + wO2 + wO3;
            dA += wA0 + wA1 + wA2 + wA3;
        }
        for (; j < end; ++j){
            int s = adj[j];
            float eO = AS[(size_t)s*4 + h];       float eA = AS[(size_t)(s+NN)*4 + h];
            unsigned uO = Hw[(size_t)s*64 + t];   unsigned uA = Hw[(size_t)(s+NN)*64 + t];
            float wO = __expf(lrelu(eO + adO));   float wA = __expf(lrelu(eA + adA));
            aO0 += __uint_as_float(uO << 16) * wO;
            aO1 += __uint_as_float(uO & 0xffff0000u) * wO;
            aA0 += __uint_as_float(uA << 16) * wA;
            aA1 += __uint_as_float(uA & 0xffff0000u) * wA;
            dO += wO; dA += wA;
        }
        float invO = 1.f/(dO + 1e-16f), invA = 1.f/(dA + 1e-16f);
        float vO0 = aO0*invO + bb0, vO1 = aO1*invO + bb1;
        float vA0 = aA0*invA + bb0, vA1 = aA1*invA + bb1;
        vO0 = (vO0 >= 0.f) ? vO0 : pp0*vO0;
        vO1 = (vO1 >= 0.f) ? vO1 : pp1*vO1;
        vA0 = (vA0 >= 0.f) ? vA0 : pp0*vA0;
        vA1 = (vA1 >= 0.f) ? vA1 : pp1*vA1;
        *(ushort2*)(outB + (size_t)g*128 + 2*t) =
            make_ushort2((unsigned short)f2bs(vO0), (unsigned short)f2bs(vO1));
        *(ushort2*)(outB + (size_t)(g+NN)*128 + 2*t) =
            make_ushort2((unsigned short)f2bs(vA0), (unsigned short)f2bs(vA1));
    }
}

__global__ __launch_bounds__(256) void gat_agg_l2(
        const int* __restrict__ row, const int* __restrict__ adj,
        const __hip_bfloat16* __restrict__ Hfeat,
        const float* __restrict__ AS, const float* __restrict__ AD,
        const float* __restrict__ b, const float* __restrict__ p,
        float* __restrict__ outO, float* __restrict__ outA){
    const int wv = (blockIdx.x*blockDim.x + threadIdx.x) >> 6;
    const int nw = (gridDim.x*blockDim.x) >> 6;
    const int t = threadIdx.x & 63;
    const float bb = b[t], pp = p[t];
    const ushort* Hu = (const ushort*)Hfeat;
    for (int g = wv; g < NN; g += nw){
        const float adO = AD[g], adA = AD[g+NN];
        float aO, dO, aA, dA;
        {   // self loops
            float wsO = __expf(lrelu(AS[g] + adO));
            float wsA = __expf(lrelu(AS[g+NN] + adA));
            unsigned uO = Hu[(size_t)g*64 + t];
            unsigned uA = Hu[(size_t)(g+NN)*64 + t];
            aO = __uint_as_float(uO << 16) * wsO;
            aA = __uint_as_float(uA << 16) * wsA;
            dO = wsO; dA = wsA;
        }
        const int beg = row[g], end = row[g+1];
        int j = beg;
        for (; j + 3 < end; j += 4){
            int s0 = adj[j];   int s1 = adj[j+1];
            int s2 = adj[j+2]; int s3 = adj[j+3];
            float eO0 = AS[s0];      float eA0 = AS[s0+NN];
            float eO1 = AS[s1];      float eA1 = AS[s1+NN];
            float eO2 = AS[s2];      float eA2 = AS[s2+NN];
            float eO3 = AS[s3];      float eA3 = AS[s3+NN];
            unsigned uO0 = Hu[(size_t)s0*64 + t];  unsigned uA0 = Hu[(size_t)(s0+NN)*64 + t];
            unsigned uO1 = Hu[(size_t)s1*64 + t];  unsigned uA1 = Hu[(size_t)(s1+NN)*64 + t];
            unsigned uO2 = Hu[(size_t)s2*64 + t];  unsigned uA2 = Hu[(size_t)(s2+NN)*64 + t];
            unsigned uO3 = Hu[(size_t)s3*64 + t];  unsigned uA3 = Hu[(size_t)(s3+NN)*64 + t];
            float wO0 = __expf(lrelu(eO0 + adO));  float wA0 = __expf(lrelu(eA0 + adA));
            float wO1 = __expf(lrelu(eO1 + adO));  float wA1 = __expf(lrelu(eA1 + adA));
            float wO2 = __expf(lrelu(eO2 + adO));  float wA2 = __expf(lrelu(eA2 + adA));
            float wO3 = __expf(lrelu(eO3 + adO));  float wA3 = __expf(lrelu(eA3 + adA));
            aO += __uint_as_float(uO0 << 16) * wO0;
            aO += __uint_as_float(uO1 << 16) * wO1;
            aO += __uint_as_float(uO2 << 16) * wO2;
            aO += __uint_as_float(uO3 << 16) * wO3;
            aA += __uint_as_float(uA0 << 16) * wA0;
            aA += __uint_as_float(uA1 << 16) * wA1;
            aA += __uint_as_float(uA2 << 16) * wA2;
            aA += __uint_as_float(uA3 << 16) * wA3;
            dO += wO0 + wO1 + wO2 + wO3;
            dA += wA0 + wA1 + wA2 + wA3;
        }
        for (; j < end; ++j){
            int s = adj[j];
            float eO = AS[s];                    float eA = AS[s+NN];
            unsigned uO = Hu[(size_t)s*64 + t];  unsigned uA = Hu[(size_t)(s+NN)*64 + t];
            float wO = __expf(lrelu(eO + adO));  float wA = __expf(lrelu(eA + adA));
            aO += __uint_as_float(uO << 16) * wO;
            aA += __uint_as_float(uA << 16) * wA;
            dO += wO; dA += wA;
        }
        float vO = aO/(dO + 1e-16f) + bb;
        float vA = aA/(dA + 1e-16f) + bb;
        vO = (vO >= 0.f) ? vO : pp*vO;
        vA = (vA >= 0.f) ? vA : pp*vA;
        outO[(size_t)g*64 + t] = vO;
        outA[(size_t)g*64 + t] = vA;
    }
}

// ---------------- both column sums in one launch ----------------
__global__ __launch_bounds__(256) void colsum2(const float* __restrict__ Xo,
                                               const float* __restrict__ Xa,
                                               float* __restrict__ outO,
                                               float* __restrict__ outA){
    __shared__ float red[2][256];
    const int t = threadIdx.x;
    const int c = t & 63;
    const int rg = t >> 6;
    float so = 0.f, sa = 0.f;
    for (int r = blockIdx.x*4 + rg; r < NN; r += gridDim.x*4){
        so += Xo[(size_t)r*64 + c];
        sa += Xa[(size_t)r*64 + c];
    }
    red[0][t] = so; red[1][t] = sa; __syncthreads();
    if (t < 64){
        atomicAdd(&outO[c], red[0][t] + red[0][t+64] + red[0][t+128] + red[0][t+192]);
        atomicAdd(&outA[c], red[1][t] + red[1][t+64] + red[1][t+128] + red[1][t+192]);
    }
}

__global__ void summary(const float* __restrict__ csum_o, const float* __restrict__ csum_a,
                        const float* __restrict__ mlpW, const float* __restrict__ mlpb,
                        const float* __restrict__ discW,
                        const float* __restrict__ advW, const float* __restrict__ advb,
                        float* __restrict__ Wc_o, float* __restrict__ Wc_a,
                        float* __restrict__ advRow, float* __restrict__ advbsum){
    __shared__ float s_o[64], s_a[64], h_o[64], h_a[64];
    const int t = threadIdx.x;
    s_o[t] = 1.f/(1.f + expf(-csum_o[t]/(float)NN));
    s_a[t] = 1.f/(1.f + expf(-csum_a[t]/(float)NN));
    __syncthreads();
    float ao = 0.f, aa = 0.f;
    for (int k = 0; k < 64; ++k){ float w = mlpW[k*64 + t]; ao += s_o[k]*w; aa += s_a[k]*w; }
    float bb = mlpb[t];
    h_o[t] = ao + bb; h_a[t] = aa + bb;
    __syncthreads();
    float wo = 0.f, wa = 0.f;
    for (int j = 0; j < 64; ++j){ float w = discW[t*64 + j]; wo += w*h_o[j]; wa += w*h_a[j]; }
    Wc_o[t] = wo; Wc_a[t] = wa;
    float ar = 0.f;
    for (int j = 0; j < 64; ++j) ar += advW[t*64 + j];
    advRow[t] = ar;
    float ab = advb[t];
    for (int o = 32; o > 0; o >>= 1) ab += __shfl_down(ab, o, 64);
    if (t == 0) advbsum[0] = ab;
}

__global__ void node_outputs(const float* __restrict__ x2o, const float* __restrict__ x2a,
                             const float* __restrict__ Wc_o, const float* __restrict__ Wc_a,
                             const float* __restrict__ advRow, const float* __restrict__ advbsum,
                             const float* __restrict__ discb,
                             float* __restrict__ out){
    const int n = blockIdx.x*4 + (threadIdx.x >> 6);
    const int l = threadIdx.x & 63;
    float xo = x2o[(size_t)n*64 + l], xa = x2a[(size_t)n*64 + l];
    float wo = Wc_o[l], wa = Wc_a[l], ar = advRow[l];
    float d1 = xo*wo, d2 = xa*wo, d3 = xa*wa, d4 = xo*wa, d5 = xo*ar, d6 = xa*ar;
    for (int o = 32; o > 0; o >>= 1){
        d1 += __shfl_down(d1, o, 64); d2 += __shfl_down(d2, o, 64);
        d3 += __shfl_down(d3, o, 64); d4 += __shfl_down(d4, o, 64);
        d5 += __shfl_down(d5, o, 64); d6 += __shfl_down(d6, o, 64);
    }
    if (l == 0){
        float db = discb[0];
        float ab = advbsum[0];
        out[O_RETOS  + n*2 + 0] = d1 + db;
        out[O_RETOS  + n*2 + 1] = d2 + db;
        out[O_RETOSA + n*2 + 0] = d3 + db;
        out[O_RETOSA + n*2 + 1] = d4 + db;
        out[O_LOGITS + n]       = d5 + ab;
        out[O_LOGITS + NN + n]  = d6 + ab;
    }
}

// ---------------- fused decoder: MFMA fh + both heads, 16 pairs/block --------
__global__ __launch_bounds__(256) void decoder_fused(
        const float* __restrict__ x2o, const int* __restrict__ idxArr,
        const __hip_bfloat16* __restrict__ Wpkf, const float* __restrict__ fb1,
        const float* __restrict__ fW2, const float* __restrict__ fb2,
        const float* __restrict__ fW3, const float* __restrict__ fb3,
        float* __restrict__ out){
    __shared__ float part[4][16][4];
    const int t = threadIdx.x;
    const int wid = t >> 6, lane = t & 63;
    const int arow = lane & 15, quad = lane >> 4;
    const int p0 = blockIdx.x*16;
    const int i0 = idxArr[p0 + arow];
    const int i1 = idxArr[BP + p0 + arow];

    f32x4 acc[8];
    #pragma unroll
    for (int c = 0; c < 8; ++c) acc[c] = (f32x4){0.f,0.f,0.f,0.f};

    #pragma unroll
    for (int kb = 0; kb < 4; ++kb){
        int src = (kb < 2) ? i0 : i1;
        int koff = (kb & 1)*32 + quad*8;
        const float* ap = x2o + (size_t)src*64 + koff;
        float4 v0 = *(const float4*)ap;
        float4 v1 = *(const float4*)(ap + 4);
        short8 af;
        af[0]=f2bs(v0.x); af[1]=f2bs(v0.y); af[2]=f2bs(v0.z); af[3]=f2bs(v0.w);
        af[4]=f2bs(v1.x); af[5]=f2bs(v1.y); af[6]=f2bs(v1.z); af[7]=f2bs(v1.w);
        const __hip_bfloat16* wp = Wpkf + (size_t)kb*32*64*8;
        #pragma unroll
        for (int c = 0; c < 8; ++c){
            int ct = wid*8 + c;
            short8 bfr = *(const short8*)(wp + ((size_t)ct*64 + lane)*8);
            acc[c] = __builtin_amdgcn_mfma_f32_16x16x32_bf16(af, bfr, acc[c], 0, 0, 0);
        }
    }

    float a0[4] = {0,0,0,0}, a1[4] = {0,0,0,0};
    float c0[4] = {0,0,0,0}, c1[4] = {0,0,0,0};
    #pragma unroll
    for (int c = 0; c < 8; ++c){
        int col = wid*128 + c*16 + arow;
        float bb = fb1[col];
        float w20 = fW2[col*2], w21 = fW2[col*2+1];
        float w30 = fW3[col*2], w31 = fW3[col*2+1];
        #pragma unroll
        for (int r = 0; r < 4; ++r){
            float v = acc[c][r] + bb;
            v = (v > 0.f) ? v : 0.f;
            a0[r] += v*w20; a1[r] += v*w21;
            c0[r] += v*w30; c1[r] += v*w31;
        }
    }
    #pragma unroll
    for (int o = 8; o > 0; o >>= 1){
        #pragma unroll
        for (int r = 0; r < 4; ++r){
            a0[r] += __shfl_down(a0[r], o, 16);
            a1[r] += __shfl_down(a1[r], o, 16);
            c0[r] += __shfl_down(c0[r], o, 16);
            c1[r] += __shfl_down(c1[r], o, 16);
        }
    }
    if (arow == 0){
        #pragma unroll
        for (int r = 0; r < 4; ++r){
            part[wid][quad*4 + r][0] = a0[r];
            part[wid][quad*4 + r][1] = a1[r];
            part[wid][quad*4 + r][2] = c0[r];
            part[wid][quad*4 + r][3] = c1[r];
        }
    }
    __syncthreads();
    if (t < 64){
        int pr = t >> 2, o = t & 3;
        float s = part[0][pr][o] + part[1][pr][o] + part[2][pr][o] + part[3][pr][o];
        int gb = p0 + pr;
        if (o == 0)      out[O_LOG  + gb*2 + 0] = s + fb2[0];
        else if (o == 1) out[O_LOG  + gb*2 + 1] = s + fb2[1];
        else if (o == 2) out[O_LOG1 + gb*2 + 0] = s + fb3[0];
        else             out[O_LOG1 + gb*2 + 1] = s + fb3[1];
    }
}

extern "C" void kernel_launch(void* const* d_in, const int* in_sizes, int n_in,
                              void* d_out, int out_size, void* d_ws, size_t ws_size,
                              hipStream_t stream){
    const float* x_o    = (const float*)d_in[0];
    const float* x_a    = (const float*)d_in[1];
    const int*   edge   = (const int*)d_in[2];
    const int*   idxp   = (const int*)d_in[3];
    const float* W1     = (const float*)d_in[4];
    const float* a_src1 = (const float*)d_in[5];
    const float* a_dst1 = (const float*)d_in[6];
    const float* b1     = (const float*)d_in[7];
    const float* p1     = (const float*)d_in[8];
    const float* W2     = (const float*)d_in[9];
    const float* a_src2 = (const float*)d_in[10];
    const float* a_dst2 = (const float*)d_in[11];
    const float* b2     = (const float*)d_in[12];
    const float* p2     = (const float*)d_in[13];
    const float* mlpW   = (const float*)d_in[14];
    const float* mlpb   = (const float*)d_in[15];
    const float* discW  = (const float*)d_in[16];
    const float* discb  = (const float*)d_in[17];
    const float* advW   = (const float*)d_in[18];
    const float* advb   = (const float*)d_in[19];
    const float* fW1    = (const float*)d_in[20];
    const float* fb1    = (const float*)d_in[21];
    const float* fW2    = (const float*)d_in[22];
    const float* fb2    = (const float*)d_in[23];
    const float* fW3    = (const float*)d_in[24];
    const float* fb3    = (const float*)d_in[25];

    const int* esrc = edge;
    const int* edst = edge + EE;

    // workspace carve-up (fp32 units), ~58 MB total
    float* w = (float*)d_ws;
    size_t off = 0;
    auto alloc = [&](size_t nfloats){ float* p = w + off; off += nfloats; return p; };
    __hip_bfloat16* Hb   = (__hip_bfloat16*)alloc((size_t)N2*M1/2);  // 2N x 128 bf16
    __hip_bfloat16* x1b  = (__hip_bfloat16*)alloc((size_t)N2*M1/2);  // 2N x 128 bf16
    float* asb   = alloc((size_t)N2*H1N);
    float* adb   = alloc((size_t)N2*H1N);
    __hip_bfloat16* Wpk1 = (__hip_bfloat16*)alloc((size_t)DIN*M1/2);
    __hip_bfloat16* Wpk2 = (__hip_bfloat16*)alloc((size_t)M1*M2/2);
    __hip_bfloat16* Wpkf = (__hip_bfloat16*)alloc((size_t)M1*DEC/2);
    int*   cnt   = (int*)alloc(NN);
    int*   row   = (int*)alloc(NN + 1);
    int*   cursor= (int*)alloc(NN);
    int*   adj   = (int*)alloc(EE);
    int*   bsum  = (int*)alloc(SCAN_NB + 1);
    float* smallb= alloc(512);
    float* csum_o = smallb;       float* csum_a = smallb + 64;
    float* Wc_o   = smallb + 128; float* Wc_a   = smallb + 192;
    float* advRow = smallb + 256; float* advbs  = smallb + 320;

    // x2a aliases the x1b region (x1b dead after layer-2 GEMM reads it).
    float* x2a = (float*)x1b;

    float* out = (float*)d_out;
    float* x2o = out + O_X2;   // agg_l2 writes x2o straight into the output

    // ---- CSR build + W packing ----
    hipMemsetAsync(cnt, 0, NN*sizeof(int), stream);
    hipMemsetAsync(smallb, 0, 128*sizeof(float), stream);
    hist_dst<<<(EE + 255)/256, 256, 0, stream>>>(edst, cnt);
    scan_blk<<<SCAN_NB, 1024, 0, stream>>>(cnt, row, bsum);
    scan_bsum<<<1, 64, 0, stream>>>(bsum, SCAN_NB);
    scan_fix<<<(NN + 255)/256, 256, 0, stream>>>(row, bsum, cursor);
    fill_csr<<<(EE + 255)/256, 256, 0, stream>>>(esrc, edst, cursor, adj);
    pack_all<<<(DIN*M1 + M1*M2 + M1*DEC + 255)/256, 256, 0, stream>>>(
        W1, W2, fW1, Wpk1, Wpk2, Wpkf);

    // ---- layer 1 (both encoders batched) ----
    gemm_attn<DIN, M1, H1N, true><<<512, 256, 0, stream>>>(
        x_o, x_a, Wpk1, a_src1, a_dst1, Hb, asb, adb);
    gat_agg_l1<<<2048, 256, 0, stream>>>(row, adj, Hb, asb, adb, b1, p1, x1b);

    // ---- layer 2 (both encoders batched) ----
    gemm_attn<M1, M2, 1, false><<<1024, 256, 0, stream>>>(
        x1b, nullptr, Wpk2, a_src2, a_dst2, Hb, asb, adb);
    gat_agg_l2<<<2048, 256, 0, stream>>>(row, adj, Hb, asb, adb, b2, p2, x2o, x2a);

    // ---- readout / heads ----
    colsum2<<<256, 256, 0, stream>>>(x2o, x2a, csum_o, csum_a);
    summary<<<1, 64, 0, stream>>>(csum_o, csum_a, mlpW, mlpb, discW, advW, advb,
                                  Wc_o, Wc_a, advRow, advbs);
    node_outputs<<<NN/4, 256, 0, stream>>>(x2o, x2a, Wc_o, Wc_a, advRow, advbs, discb, out);
    decoder_fused<<<BP/16, 256, 0, stream>>>(x2o, idxp, Wpkf, fb1, fW2, fb2, fW3, fb3, out);
}